// Round 3
// baseline (96.059 us; speedup 1.0000x reference)
//
#include <hip/hip_runtime.h>

// GruDirection3d forward, d1=d2=d3=1. B=2, C=96, D=H=W=32.
// out[b,c,d,y,x] = z*h_tilde + (1-z)*out[b,c,d-1,y-1,x-1], border = h0.
//
// Plane-wavefront DP, full register preload, RAW barriers.
//
// One 1024-thread block per (b,c) slab; thread (y,x) owns one element of
// every d-plane. All 32 planes of z and h_tilde (64 floats/thread) are
// issued as one coalesced burst of 64 outstanding dword loads; the compiler
// inserts exact per-plane vmcnt(N) waits, so the d-sweep starts as soon as
// plane 0 lands and HBM streaming overlaps the recurrence.
//
// CRITICAL FIX vs round 2: __syncthreads() compiles to
//   s_waitcnt vmcnt(0) expcnt(0) lgkmcnt(0); s_barrier
// which drains the ENTIRE preload burst at the first barrier (serializing
// stream vs recurrence) and drains each step's global store on the critical
// path. We only need LDS ordering, so we use the HipKittens idiom:
//   s_waitcnt lgkmcnt(0); s_barrier   (raw, no vmcnt drain)
// Double-buffered LDS handles WAR: each wave's lgkmcnt(0) covers both its
// buf write AND its shifted read, so one barrier per plane suffices.
//
// Shifted read (y-1,x-1) = tid-33: stride-1 across lanes -> conflict-free.

#define PLANE 1024              // 32*32
#define DD 32

// LDS-only barrier: order LDS ops, leave global loads/stores in flight.
#define LDS_BARRIER()                                        \
    do {                                                     \
        asm volatile("s_waitcnt lgkmcnt(0)" ::: "memory");   \
        __builtin_amdgcn_s_barrier();                        \
    } while (0)

__global__ __launch_bounds__(1024) void gru3d_rawbar(
    const float* __restrict__ z,
    const float* __restrict__ ht,
    const float* __restrict__ h0p,
    float* __restrict__ out)
{
    __shared__ float buf[2][PLANE];

    const int bc  = blockIdx.x;           // 0..191
    const int tid = threadIdx.x;          // y*32 + x
    const int y   = tid >> 5;
    const int x   = tid & 31;

    const float* zb = z   + (size_t)bc * (DD * PLANE);
    const float* tb = ht  + (size_t)bc * (DD * PLANE);
    float*       ob = out + (size_t)bc * (DD * PLANE);

    const float h0 = h0p[0];

    // Bulk preload: 64 coalesced dword loads, all in flight at once.
    float zr[DD], tr[DD];
    #pragma unroll
    for (int d = 0; d < DD; ++d) {
        zr[d] = zb[d * PLANE + tid];
        tr[d] = tb[d * PLANE + tid];
    }

    const bool interior = (y > 0) & (x > 0);

    // d = 0: predecessor is the h0 border everywhere.
    float h = zr[0] * (tr[0] - h0) + h0;   // == z*ht + (1-z)*h0
    ob[tid] = h;
    buf[0][tid] = h;
    LDS_BARRIER();

    #pragma unroll
    for (int d = 1; d < DD; ++d) {
        const float pv = interior ? buf[(d - 1) & 1][tid - 33] : h0;
        const float hn = zr[d] * (tr[d] - pv) + pv;
        ob[d * PLANE + tid] = hn;          // fire-and-forget, never drained
        buf[d & 1][tid] = hn;
        LDS_BARRIER();
    }
}

extern "C" void kernel_launch(void* const* d_in, const int* in_sizes, int n_in,
                              void* d_out, int out_size, void* d_ws, size_t ws_size,
                              hipStream_t stream) {
    const float* z  = (const float*)d_in[0];
    const float* ht = (const float*)d_in[1];
    const float* h0 = (const float*)d_in[2];
    float* out      = (float*)d_out;

    const int BC = 2 * 96;                // 192 slabs, one block each
    gru3d_rawbar<<<dim3(BC), dim3(1024), 0, stream>>>(z, ht, h0, out);
}

// Round 4
// 95.936 us; speedup vs baseline: 1.0013x; 1.0013x over previous
//
#include <hip/hip_runtime.h>

// GruDirection3d forward, d1=d2=d3=1. B=2, C=96, D=H=W=32.
// out[b,c,d,y,x] = z*h_tilde + (1-z)*out[b,c,d-1,y-1,x-1], border = h0.
//
// Plane-wavefront DP, float4 everywhere. One 256-thread block per (b,c)
// slab; thread (y, xg) owns x = 4*xg..4*xg+3 of every d-plane. All global
// traffic is dwordx4 (1KB/wave-instr): round-3 post-mortem showed the
// scalar-dword version stuck at ~5 B/cy/CU, half the float4 streaming rate.
//
// Inputs stream through a depth-8 register ring (fully unrolled -> static
// indices -> VGPRs, no scratch): 16 outstanding wide loads per wave, so HBM
// latency and the serial d-sweep overlap.
//
// Diagonal predecessor (y-1,x-1) from double-buffered LDS h-plane:
//   pv[1..3] = ds_read_b128 row y-1, cols x0..x0+2   (8 lanes = 1 row
//              covers all 32 banks -> conflict-free)
//   pv[0]    = ds_read_b32  row y-1, col x0-1        (4-way, negligible)
// Raw lgkmcnt-only barrier keeps the global stores fire-and-forget.

#define PLANE 1024              // 32*32 floats per plane
#define DD    32
#define PF    8                 // prefetch ring depth (planes)

#define LDS_BARRIER()                                        \
    do {                                                     \
        asm volatile("s_waitcnt lgkmcnt(0)" ::: "memory");   \
        __builtin_amdgcn_s_barrier();                        \
    } while (0)

__global__ __launch_bounds__(256) void gru3d_vec4(
    const float* __restrict__ z,
    const float* __restrict__ ht,
    const float* __restrict__ h0p,
    float* __restrict__ out)
{
    __shared__ float hbuf[2][PLANE];

    const int bc  = blockIdx.x;          // 0..191
    const int tid = threadIdx.x;         // y*8 + xg
    const int y   = tid >> 3;
    const int xg  = tid & 7;
    const int x0  = xg << 2;
    const int off0 = y * 32 + x0;        // float offset within a plane

    const float* zb = z   + (size_t)bc * (DD * PLANE);
    const float* tb = ht  + (size_t)bc * (DD * PLANE);
    float*       ob = out + (size_t)bc * (DD * PLANE);

    const float h0 = h0p[0];

    // Prologue: fill the ring with planes 0..PF-1 (interleaved z/ht).
    float4 zr[PF], tr[PF];
    #pragma unroll
    for (int p = 0; p < PF; ++p) {
        zr[p] = *reinterpret_cast<const float4*>(zb + p * PLANE + off0);
        tr[p] = *reinterpret_cast<const float4*>(tb + p * PLANE + off0);
    }

    float4 h;

    // d = 0: predecessor is the h0 border everywhere.
    {
        const float4 zv = zr[0], tv = tr[0];
        h.x = zv.x * (tv.x - h0) + h0;
        h.y = zv.y * (tv.y - h0) + h0;
        h.z = zv.z * (tv.z - h0) + h0;
        h.w = zv.w * (tv.w - h0) + h0;
        *reinterpret_cast<float4*>(&hbuf[0][off0]) = h;          // ds_write_b128
        *reinterpret_cast<float4*>(ob + off0) = h;               // fire-and-forget
        zr[0] = *reinterpret_cast<const float4*>(zb + PF * PLANE + off0);
        tr[0] = *reinterpret_cast<const float4*>(tb + PF * PLANE + off0);
        LDS_BARRIER();
    }

    #pragma unroll
    for (int d = 1; d < DD; ++d) {
        const int s  = d & (PF - 1);
        const int pb = (d - 1) & 1;
        const float4 zv = zr[s], tv = tr[s];

        // Predecessor values out[d-1, y-1, x0-1 .. x0+2].
        float pv0, pv1, pv2, pv3;
        if (y == 0) {
            pv0 = pv1 = pv2 = pv3 = h0;
        } else {
            const float4 q = *reinterpret_cast<const float4*>(&hbuf[pb][off0 - 32]);
            pv1 = q.x; pv2 = q.y; pv3 = q.z;
            const int il = (off0 - 33 < 0) ? 0 : (off0 - 33);    // clamp y==1,x0==0
            const float left = hbuf[pb][il];
            pv0 = (x0 > 0) ? left : h0;
        }

        h.x = zv.x * (tv.x - pv0) + pv0;
        h.y = zv.y * (tv.y - pv1) + pv1;
        h.z = zv.z * (tv.z - pv2) + pv2;
        h.w = zv.w * (tv.w - pv3) + pv3;

        *reinterpret_cast<float4*>(&hbuf[d & 1][off0]) = h;      // LDS first
        *reinterpret_cast<float4*>(ob + d * PLANE + off0) = h;   // then global

        if (d + PF < DD) {                                       // refill ring
            zr[s] = *reinterpret_cast<const float4*>(zb + (d + PF) * PLANE + off0);
            tr[s] = *reinterpret_cast<const float4*>(tb + (d + PF) * PLANE + off0);
        }
        LDS_BARRIER();
    }
}

extern "C" void kernel_launch(void* const* d_in, const int* in_sizes, int n_in,
                              void* d_out, int out_size, void* d_ws, size_t ws_size,
                              hipStream_t stream) {
    const float* z  = (const float*)d_in[0];
    const float* ht = (const float*)d_in[1];
    const float* h0 = (const float*)d_in[2];
    float* out      = (float*)d_out;

    const int BC = 2 * 96;               // 192 slabs, one block each
    gru3d_vec4<<<dim3(BC), dim3(256), 0, stream>>>(z, ht, h0, out);
}

// Round 5
// 92.587 us; speedup vs baseline: 1.0375x; 1.0362x over previous
//
#include <hip/hip_runtime.h>

// GruDirection3d forward, d1=d2=d3=1. B=2, C=96, D=H=W=32.
// out[b,c,d,y,x] = z*h_tilde + (1-z)*out[b,c,d-1,y-1,x-1], border = h0.
//
// HELIX DECOMPOSITION: thread (a,b) owns, at plane d, the voxel
//     y = (a+d) & 31,  x = (b+d) & 31.
// This is a bijection per plane, and the diagonal predecessor
// (d-1, y-1, x-1) is the SAME thread's previous voxel whenever y>0 && x>0;
// a wrap (y==0 || x==0) means the voxel sits on the padded border, whose
// predecessor is exactly h0 (chain reset). d=0 is handled by initializing
// h = h0 (interior plane-0 voxels read the h0 border through the same
// predicate path).
//
// Consequences:
//   - recurrence is register-resident: NO LDS, NO barriers, NO cross-thread
//     communication of h at all (rounds 2-4 showed the sync machinery was
//     neutral; this removes it entirely),
//   - a wave's 64 lanes cover two full 32-float rows, cyclically rotated ->
//     the SAME dense 128-B lines as an unrotated row -> perfectly coalesced
//     loads and stores,
//   - chains are fully independent -> split each slab's 1024 chains over 4
//     blocks: 768 blocks x 256 threads = 3 blocks/CU on ALL 256 CUs
//     (previous kernels idled 64 CUs with their 192-block grids).
//
// Inputs stream through a depth-8 register ring (static indices under full
// unroll -> VGPRs): 16 outstanding dword loads/thread, ~48 KB in flight per
// CU, so HBM latency is covered many times over.

#define DD 32
#define PF 8                    // prefetch ring depth (planes)

__global__ __launch_bounds__(256) void gru3d_helix(
    const float* __restrict__ z,
    const float* __restrict__ ht,
    const float* __restrict__ h0p,
    float* __restrict__ out)
{
    const int blk  = blockIdx.x;         // 0..767 = slab*4 + agrp
    const int slab = blk >> 2;           // 0..191  (b*96 + c)
    const int agrp = blk & 3;            // which 8-row band of 'a'
    const int tid  = threadIdx.x;        // 0..255
    const int a    = (agrp << 3) + (tid >> 5);
    const int b    = tid & 31;

    const float h0 = h0p[0];

    const size_t base = (size_t)slab * (DD * 1024);
    const float* __restrict__ zb = z   + base;
    const float* __restrict__ tb = ht  + base;
    float*       __restrict__ ob = out + base;

    // Offset within the slab of this thread's voxel at plane d.
    // Pure bit-concat: addr = d*1024 + y*32 + x with y,x in [0,32).
    auto off = [&](int d) -> int {
        return (d << 10) | (((a + d) & 31) << 5) | ((b + d) & 31);
    };

    // Prologue: fill the ring with planes 0..PF-1.
    float zr[PF], tr[PF];
    #pragma unroll
    for (int p = 0; p < PF; ++p) {
        zr[p] = zb[off(p)];
        tr[p] = tb[off(p)];
    }

    float h = h0;                        // plane -1 "value": the border

    #pragma unroll
    for (int d = 0; d < DD; ++d) {
        const int s = d & (PF - 1);

        // Border reset: voxel is on the y==0 or x==0 face -> pred = h0.
        const bool border = (((a + d) & 31) == 0) | (((b + d) & 31) == 0);
        const float pred  = border ? h0 : h;

        h = zr[s] * (tr[s] - pred) + pred;   // z*ht + (1-z)*pred
        ob[off(d)] = h;                      // coalesced rotated-row store

        if (d + PF < DD) {                   // refill ring
            zr[s] = zb[off(d + PF)];
            tr[s] = tb[off(d + PF)];
        }
    }
}

extern "C" void kernel_launch(void* const* d_in, const int* in_sizes, int n_in,
                              void* d_out, int out_size, void* d_ws, size_t ws_size,
                              hipStream_t stream) {
    const float* z  = (const float*)d_in[0];
    const float* ht = (const float*)d_in[1];
    const float* h0 = (const float*)d_in[2];
    float* out      = (float*)d_out;

    const int BC = 2 * 96;               // 192 slabs, 4 blocks each
    gru3d_helix<<<dim3(BC * 4), dim3(256), 0, stream>>>(z, ht, h0, out);
}